// Round 16
// baseline (442.776 us; speedup 1.0000x reference)
//
#include <hip/hip_runtime.h>

#define F1 62400
#define O1 800
#define O2N 100
#define TT 300
#define BB 2
#define NWRD 975        /* 64-bit f-words */
#define KSRM 77
#define KREF 11
#define MB 25           /* M-blocks of 32 o */
#define NPAD 640        /* n = b*320 + t */
#define NDIG 4          /* base-256 digits of rint(w1 * 2^31) — exact (R4-proven) */
#define KSPL 10         /* k-splits */
#define WPS 98          /* words per split (last split: 93) */
#define ASTRIDE ((size_t)MB * NDIG * 2048)
#define BSTRIDE ((size_t)NPAD * 4)

typedef unsigned long long u64;
typedef int i32x4 __attribute__((ext_vector_type(4)));

/* ---- ws layout (bytes); NEED ~218.8 MB (proven available) ---- */
#define OFF_CONST 0ull
#define OFF_Z1I  1024ull
#define OFF_S1T  (OFF_Z1I + 4096000ull)
#define OFF_XBW  (OFF_S1T + 1920000ull)          /* 975*640*8 (320-stride, pad stored 0) */
#define OFF_Z1F  (OFF_XBW + 4992000ull)
#define OFF_AQ   (OFF_Z1F + 3840000ull)          /* 975*25*4*2048 = 199,680,000 */
#define NEED_SPARSE (OFF_AQ + 199680000ull)

#define GLOAD_LDS16(g, s) __builtin_amdgcn_global_load_lds( \
    (const __attribute__((address_space(1))) unsigned int*)(g), \
    (__attribute__((address_space(3))) unsigned int*)(s), 16, 0, 0)

/* K0: SRM/REF kernels, fp64 rounded through fp32 (matches np.float32). */
__global__ void k0_init(double* c) {
    int k = threadIdx.x;
    if (k < KSRM) {
        double v = ((double)k / 10.0) * exp(1.0 - (double)k / 10.0);
        c[k] = (double)(float)v;
    }
    if (k < KREF) {
        double v = -20.0 * (double)k * exp(1.0 - (double)k);
        c[80 + k] = (double)(float)v;
    }
}

/* K1: bitmask xbw[w][b*320+t]: bit j = (x[b][w*64+j][t] > 0.5). Pad t -> 0. */
__global__ __launch_bounds__(256) void k1_xbw(const float* __restrict__ x,
                                              u64* __restrict__ xbw) {
    const int NTG = 5;
    int gw = (blockIdx.x * 256 + threadIdx.x) >> 6;
    int lane = threadIdx.x & 63;
    if (gw >= BB * NWRD * NTG) return;
    int b  = gw / (NWRD * NTG);
    int r  = gw % (NWRD * NTG);
    int fw = r / NTG;
    int tg = r % NTG;
    int t = tg * 64 + lane;          /* always < 320 */
    bool act = (t < TT);
    int tc = act ? t : 0;
    const float* xp = x + ((size_t)(b * F1 + (fw << 6))) * TT + tc;
    unsigned lo = 0, hi = 0;
    #pragma unroll
    for (int j = 0; j < 32; ++j)
        lo |= (xp[(size_t)j * TT] > 0.5f ? 1u : 0u) << j;
    #pragma unroll
    for (int j = 0; j < 32; ++j)
        hi |= (xp[(size_t)(j + 32) * TT] > 0.5f ? 1u : 0u) << j;
    u64 mval = act ? (((u64)hi << 32) | lo) : 0ull;
    xbw[(size_t)fw * NPAD + b * 320 + t] = mval;
}

/* K_QA: quantize all w1 words -> 4 digit planes (scale 2^31, exact) in
   LANE-LINEAR fragment order: within dig plane, lane l of o-half oh owns
   bytes [oh*1024 + l*16, +16) where l = kc*16 + (o&15). Conflict-free
   ds_read_b128 in k3m2 (lane l -> byte l*16, contiguous 1KB/wave). */
__global__ __launch_bounds__(256) void k_qa(const float* __restrict__ w1,
                                            char* __restrict__ aq) {
    int tid = blockIdx.x * 256 + threadIdx.x;
    if (tid >= NWRD * 3200) return;
    int kc = tid & 3;
    int o  = (tid >> 2) & 31;
    int m  = (tid >> 7) % MB;
    int wl = tid / 3200;
    const float* src = w1 + (size_t)(m * 32 + o) * F1 + (size_t)wl * 64 + kc * 16;
    unsigned dw[NDIG][4];
    #pragma unroll
    for (int g = 0; g < 4; ++g) {
        float4 f4 = *(const float4*)(src + g * 4);
        float ff[4] = {f4.x, f4.y, f4.z, f4.w};
        unsigned w0 = 0, w1_ = 0, w2 = 0, w3 = 0;
        #pragma unroll
        for (int e = 0; e < 4; ++e) {
            int v = (int)rint((double)ff[e] * 2147483648.0);   /* 2^31, exact */
            int d0 = (v << 24) >> 24;  int v1 = (v - d0) >> 8;
            int d1 = (v1 << 24) >> 24; int v2 = (v1 - d1) >> 8;
            int d2 = (v2 << 24) >> 24; int d3 = (v2 - d2) >> 8;
            w0 |= (unsigned)(d0 & 0xFF) << (8 * e);
            w1_ |= (unsigned)(d1 & 0xFF) << (8 * e);
            w2 |= (unsigned)(d2 & 0xFF) << (8 * e);
            w3 |= (unsigned)(d3 & 0xFF) << (8 * e);
        }
        dw[0][g] = w0; dw[1][g] = w1_; dw[2][g] = w2; dw[3][g] = w3;
    }
    /* lane-linear offset: half*1024 + (kc*16 + (o&15))*16 */
    char* dst = aq + (((size_t)wl * MB + m) * NDIG) * 2048
                + (o >> 4) * 1024 + (size_t)(kc * 16 + (o & 15)) * 16;
    #pragma unroll
    for (int d = 0; d < NDIG; ++d)
        *(i32x4*)(dst + (size_t)d * 2048) =
            (i32x4){(int)dw[d][0], (int)dw[d][1], (int)dw[d][2], (int)dw[d][3]};
}

/* unpack 16 mask bits -> 16 i8 (R4-verified byte order) + 4 digit MFMAs */
#define K3_COMPUTE(A0, A1, A2, A3, BV, TTI)                                        \
    {                                                                              \
        i32x4 bf;                                                                  \
        _Pragma("unroll")                                                          \
        for (int i_ = 0; i_ < 4; ++i_)                                             \
            bf[i_] = (int)((((BV >> (4 * i_)) & 0xFu) * 0x00204081u) & 0x01010101u); \
        acc[TTI][0] = __builtin_amdgcn_mfma_i32_16x16x64_i8(A0, bf, acc[TTI][0], 0, 0, 0); \
        acc[TTI][1] = __builtin_amdgcn_mfma_i32_16x16x64_i8(A1, bf, acc[TTI][1], 0, 0, 0); \
        acc[TTI][2] = __builtin_amdgcn_mfma_i32_16x16x64_i8(A2, bf, acc[TTI][2], 0, 0, 0); \
        acc[TTI][3] = __builtin_amdgcn_mfma_i32_16x16x64_i8(A3, bf, acc[TTI][3], 0, 0, 0); \
    }

/* K3M2: exact i8 MFMA GEMM; A via global_load_lds double-buffer (linear
   both sides), lane-linear conflict-free ds_read_b128 fragment loads. */
__global__ __launch_bounds__(512, 4) void k3m2(const char* __restrict__ aq,
                                               const u64* __restrict__ xbw,
                                               u64* __restrict__ z1i) {
    __shared__ __align__(16) char Abuf[2][8192];
    int m = blockIdx.x >> 1, nh = blockIdx.x & 1, ksl = blockIdx.y;
    int tid = threadIdx.x;
    int l = tid & 63, wid = tid >> 6;
    int q = wid & 3, oh = wid >> 2;

    int wl0 = ksl * WPS;
    int wend = wl0 + WPS; if (wend > NWRD) wend = NWRD;
    int steps = wend - wl0;

    i32x4 acc[5][NDIG];
    #pragma unroll
    for (int i = 0; i < 5; ++i)
        #pragma unroll
        for (int d = 0; d < NDIG; ++d) acc[i][d] = (i32x4){0, 0, 0, 0};

    const char* abase = aq + (((size_t)wl0 * MB + m) * NDIG) * 2048 + (size_t)tid * 16;
    const unsigned short* bp0 =
        (const unsigned short*)((const char*)xbw
            + ((size_t)wl0 * NPAD
               + (size_t)(nh * 320 + q * 80 + (l & 15))) * 8
            + (l >> 4) * 2);

    GLOAD_LDS16(abase, &Abuf[0][tid * 16]);
    unsigned b0 = bp0[0], b1 = bp0[64], b2 = bp0[128], b3 = bp0[192], b4 = bp0[256];
    __syncthreads();

    int cur = 0;
    /* lane-linear: lane l reads byte oh*1024 + l*16 of each dig plane */
    const int lofs = oh * 1024 + l * 16;

    for (int s = 0; s < steps; ++s) {
        if (s + 1 < steps)
            GLOAD_LDS16(abase + (size_t)(s + 1) * ASTRIDE, &Abuf[cur ^ 1][tid * 16]);
        int sn = (s + 1 < steps) ? (s + 1) : s;
        const unsigned short* bpn = bp0 + (size_t)sn * BSTRIDE;
        unsigned nb0 = bpn[0], nb1 = bpn[64], nb2 = bpn[128], nb3 = bpn[192], nb4 = bpn[256];
        const char* lp = &Abuf[cur][0] + lofs;
        i32x4 a0 = *(const i32x4*)(lp);
        i32x4 a1 = *(const i32x4*)(lp + 2048);
        i32x4 a2 = *(const i32x4*)(lp + 4096);
        i32x4 a3 = *(const i32x4*)(lp + 6144);
        K3_COMPUTE(a0, a1, a2, a3, b0, 0)
        K3_COMPUTE(a0, a1, a2, a3, b1, 1)
        K3_COMPUTE(a0, a1, a2, a3, b2, 2)
        K3_COMPUTE(a0, a1, a2, a3, b3, 3)
        K3_COMPUTE(a0, a1, a2, a3, b4, 4)
        b0 = nb0; b1 = nb1; b2 = nb2; b3 = nb3; b4 = nb4;
        __syncthreads();
        cur ^= 1;
    }

    #pragma unroll
    for (int tt = 0; tt < 5; ++tt) {
        int n = nh * 320 + q * 80 + tt * 16 + (l & 15);
        #pragma unroll
        for (int r = 0; r < 4; ++r) {
            int o = oh * 16 + (l >> 4) * 4 + r;
            long long c = (long long)acc[tt][0][r]
                        + ((long long)acc[tt][1][r] << 8)
                        + ((long long)acc[tt][2][r] << 16)
                        + ((long long)acc[tt][3][r] << 24);
            atomicAdd(&z1i[(size_t)(m * 32 + o) * NPAD + n], (u64)c);
        }
    }
}

/* dense fallback GEMM1 (used only if ws too small) -> z1f fp64 */
__global__ __launch_bounds__(256) void k_dense_gemm1(const float* __restrict__ x,
                                                     const float* __restrict__ w1,
                                                     double* __restrict__ z1) {
    int lin = blockIdx.x;
    int ot = lin % 25; int tt = (lin / 25) % 5; int b = lin / 125;
    int t0 = tt * 64, o0 = ot * 32;
    __shared__ float xs[64][64];
    __shared__ float wsh[32][64];
    int ti = threadIdx.x & 63, og = threadIdx.x >> 6;
    double dacc[8] = {0, 0, 0, 0, 0, 0, 0, 0};
    for (int fc = 0; fc < F1; fc += 64) {
        __syncthreads();
        for (int e = threadIdx.x; e < 64 * 64; e += 256) {
            int r = e >> 6, c = e & 63;
            int t = t0 + c;
            xs[r][c] = (t < TT) ? x[((size_t)b * F1 + fc + r) * TT + t] : 0.0f;
        }
        for (int e = threadIdx.x; e < 32 * 64; e += 256) {
            int r = e >> 6, c = e & 63;
            wsh[r][c] = w1[(size_t)(o0 + r) * F1 + fc + c];
        }
        __syncthreads();
        float facc[8] = {0, 0, 0, 0, 0, 0, 0, 0};
        for (int ff = 0; ff < 64; ++ff) {
            float xv = xs[ff][ti];
            #pragma unroll
            for (int oo = 0; oo < 8; ++oo) facc[oo] += wsh[og * 8 + oo][ff] * xv;
        }
        #pragma unroll
        for (int oo = 0; oo < 8; ++oo) dacc[oo] += (double)facc[oo];
    }
    int t = t0 + ti;
    if (t < TT) {
        #pragma unroll
        for (int oo = 0; oo < 8; ++oo) {
            int o = o0 + og * 8 + oo;
            z1[((size_t)(b * O1 + o)) * TT + t] = dacc[oo];
        }
    }
}

/* branch-free refractory scan over us[0..299] (LDS), executed by thread 0.
   Tree-sum order identical to the passing k_scan. */
__device__ __forceinline__ void scan_from_lds(const double* us, float* ss,
                                              const double* cst) {
    double rk1 = cst[81], rk2 = cst[82], rk3 = cst[83], rk4 = cst[84];
    double rk5 = cst[85], rk6 = cst[86], rk7 = cst[87], rk8 = cst[88];
    double rk9 = cst[89], rk10 = cst[90];
    unsigned h = 0;
    #pragma unroll 4
    for (int t = 0; t < TT; ++t) {
        double a  = ((h & 1u)   ? rk1 : 0.0) + ((h & 2u)   ? rk2  : 0.0);
        double b2 = ((h & 4u)   ? rk3 : 0.0) + ((h & 8u)   ? rk4  : 0.0);
        double c2 = ((h & 16u)  ? rk5 : 0.0) + ((h & 32u)  ? rk6  : 0.0);
        double d2 = ((h & 64u)  ? rk7 : 0.0) + ((h & 128u) ? rk8  : 0.0);
        double e2 = ((h & 256u) ? rk9 : 0.0) + ((h & 512u) ? rk10 : 0.0);
        double ueff = us[t] + (((a + b2) + (c2 + d2)) + e2);
        unsigned sp = (ueff >= 10.0) ? 1u : 0u;
        ss[t] = (float)sp;
        h = (h << 1) | sp;
    }
}

/* K_TAIL1V2: scale + psp conv (t-parallel) + branch-free in-block scan.
   Block per row (b*800+o); writes s1t[row*300+t]. */
__global__ __launch_bounds__(320) void k_tail1v2(const u64* __restrict__ z1i,
                                                 const double* __restrict__ z1f,
                                                 float* __restrict__ s1t,
                                                 const double* __restrict__ cst,
                                                 int mode) {
    __shared__ double zs[TT];
    __shared__ double us[TT];
    __shared__ float  ss[TT];
    __shared__ double ck[KSRM];
    int row = blockIdx.x;
    int b = row / O1, o = row % O1;
    int t = threadIdx.x;
    if (t < KSRM) ck[t] = cst[t];
    if (t < TT) {
        double z;
        if (mode == 0)
            z = (double)(long long)z1i[(size_t)o * NPAD + b * 320 + t]
                * 4.656612873077393e-10;                    /* 2^-31 */
        else
            z = z1f[(size_t)row * TT + t];
        zs[t] = z;
    }
    __syncthreads();
    if (t < TT) {
        int kmax = t < (KSRM - 1) ? t : (KSRM - 1);
        double acc = 0.0;
        for (int k = 0; k <= kmax; ++k) acc += ck[k] * zs[t - k];
        us[t] = acc;
    }
    __syncthreads();
    if (t == 0) scan_from_lds(us, ss, cst);
    __syncthreads();
    if (t < TT) s1t[(size_t)row * TT + t] = ss[t];
}

/* K_TAIL2V2: GEMM2 (t-parallel) + psp conv + in-block scan -> out. */
__global__ __launch_bounds__(320) void k_tail2v2(const float* __restrict__ s1t,
                                                 const float* __restrict__ w2,
                                                 float* __restrict__ out,
                                                 const double* __restrict__ cst) {
    __shared__ float wsm[O1];
    __shared__ double zs[TT];
    __shared__ double us[TT];
    __shared__ float  ss[TT];
    __shared__ double ck[KSRM];
    int bo = blockIdx.x;
    int b = bo / O2N, o2 = bo % O2N;
    int t = threadIdx.x;
    if (t < KSRM) ck[t] = cst[t];
    for (int f = t; f < O1; f += 320) wsm[f] = w2[(size_t)o2 * O1 + f];
    __syncthreads();
    if (t < TT) {
        double acc = 0.0;
        #pragma unroll 4
        for (int f = 0; f < O1; ++f)
            acc += (double)(wsm[f] * s1t[((size_t)(b * O1 + f)) * TT + t]);
        zs[t] = acc;
    }
    __syncthreads();
    if (t < TT) {
        int kmax = t < (KSRM - 1) ? t : (KSRM - 1);
        double acc = 0.0;
        for (int k = 0; k <= kmax; ++k) acc += ck[k] * zs[t - k];
        us[t] = acc;
    }
    __syncthreads();
    if (t == 0) scan_from_lds(us, ss, cst);
    __syncthreads();
    if (t < TT) out[(size_t)bo * TT + t] = ss[t];
}

extern "C" void kernel_launch(void* const* d_in, const int* in_sizes, int n_in,
                              void* d_out, int out_size, void* d_ws, size_t ws_size,
                              hipStream_t stream) {
    const float* x  = (const float*)d_in[0];
    const float* w1 = (const float*)d_in[1];
    const float* w2 = (const float*)d_in[2];
    float* out = (float*)d_out;
    char* ws = (char*)d_ws;

    double* cst = (double*)(ws + OFF_CONST);
    u64*    z1i = (u64*)   (ws + OFF_Z1I);
    float*  s1t = (float*) (ws + OFF_S1T);
    u64*    xbw = (u64*)   (ws + OFF_XBW);
    double* z1f = (double*)(ws + OFF_Z1F);
    char*   aq  = (char*)  (ws + OFF_AQ);

    k0_init<<<1, 128, 0, stream>>>(cst);

    int mode;
    if (ws_size >= NEED_SPARSE) {
        mode = 0;
        int b1 = (BB * NWRD * 5 * 64 + 255) / 256;
        k1_xbw<<<b1, 256, 0, stream>>>(x, xbw);
        hipMemsetAsync(z1i, 0, (size_t)O1 * NPAD * 8, stream);
        k_qa<<<(NWRD * 3200 + 255) / 256, 256, 0, stream>>>(w1, aq);
        k3m2<<<dim3(2 * MB, KSPL), 512, 0, stream>>>(aq, xbw, z1i);
    } else {
        mode = 1;
        k_dense_gemm1<<<250, 256, 0, stream>>>(x, w1, z1f);
    }

    k_tail1v2<<<BB * O1, 320, 0, stream>>>(z1i, z1f, s1t, cst, mode);
    k_tail2v2<<<BB * O2N, 320, 0, stream>>>(s1t, w2, out, cst);
    (void)in_sizes; (void)n_in; (void)out_size;
}